// Round 20
// baseline (280.014 us; speedup 1.0000x reference)
//
#include <hip/hip_runtime.h>
#include <math.h>
#include <stdint.h>

// Problem constants
#define LL 768
#define DIN 384
#define HH 12
#define NLIN 1080          // 192*3 + 144*2 + 216
#define WC_HALF 0.11785113019775792f   // 0.5*sqrt(2/36)
#define C_SQU 0.25f

// Workspace layout (float units)
#define OFF_LIN    0u          // 829440
#define OFF_VT     829440u     // 221184 (ushort [12][48][768]: c0-15=v1, 16-33=v3g)
#define OFF_QBH    1050624u    // 147456 (bf16 [12][768][32])
#define OFF_QBL    1198080u    // 147456
#define OFF_KBH    1345536u    // 147456
#define OFF_KBL    1492992u    // 147456
#define OFF_WZ     1640448u    // 1024   (bf16 4*64*8)
#define OFF_SQWH   1641472u    // 9216   ([12][768])
#define OFF_SKWH   1650688u    // 9216
#define OFF_SX     1659904u    // 7077888 fp32 scores; attn overwrites in-place with att;
                               //          proj's part[] aliases here after ov consumes att
#define OFF_O2     8737792u    // 147456
#define OFF_O3     8885248u    // 165888
#define OFF_O1     9051136u    // 1179648 (written directly by attn)
// end: 10230784 floats = 40.9 MB

typedef __attribute__((ext_vector_type(8))) short short8v;
typedef __attribute__((ext_vector_type(4))) float float4v;

__device__ __forceinline__ ushort f2bu(float f) {
    union { float f; uint32_t u; } v; v.f = f;
    uint32_t r = (v.u + 0x7FFFu + ((v.u >> 16) & 1u)) >> 16;
    return (ushort)r;
}
__device__ __forceinline__ float bu2f(ushort u) {
    union { uint32_t u; float f; } v; v.u = ((uint32_t)u) << 16; return v.f;
}
// LDS row swizzle: bijective within each 256-B row for j in [0,64).
__device__ __forceinline__ int fswz(int j) {
    return (((j >> 3) << 1) | ((j >> 1) & 1)) << 4;
}

// ---------------------------------------------------------------------------
// Kernel 1: lin = s @ [Wq1|Wk1|Wv1|Wq2|Wk2|Wv3]   ([768,384]@[384,1080])
// ---------------------------------------------------------------------------
__global__ __launch_bounds__(256) void gemm_lin_kernel(
    const float* __restrict__ s,
    const float* __restrict__ Wq1, const float* __restrict__ Wk1,
    const float* __restrict__ Wv1, const float* __restrict__ Wq2,
    const float* __restrict__ Wk2, const float* __restrict__ Wv3,
    float* __restrict__ lin)
{
    const int n0 = blockIdx.x * 64;
    const int i0 = blockIdx.y * 64;
    const int tid = threadIdx.x;
    __shared__ float sT[64][17];
    __shared__ float wT[16][65];
    const int tc = tid & 15, tr = tid >> 4;
    float acc[4][4] = {};
    for (int k0 = 0; k0 < DIN; k0 += 16) {
        __syncthreads();
        for (int idx = tid; idx < 1024; idx += 256) {
            int r = idx >> 4, kk = idx & 15;
            sT[r][kk] = s[(size_t)(i0 + r) * DIN + k0 + kk];
        }
        for (int idx = tid; idx < 1024; idx += 256) {
            int kk = idx >> 6, c = idx & 63;
            int col = n0 + c;
            float v = 0.f;
            if (col < NLIN) {
                const float* W; int nout, cc2;
                if      (col < 192) { W = Wq1; nout = 192; cc2 = col; }
                else if (col < 384) { W = Wk1; nout = 192; cc2 = col - 192; }
                else if (col < 576) { W = Wv1; nout = 192; cc2 = col - 384; }
                else if (col < 720) { W = Wq2; nout = 144; cc2 = col - 576; }
                else if (col < 864) { W = Wk2; nout = 144; cc2 = col - 720; }
                else                { W = Wv3; nout = 216; cc2 = col - 864; }
                v = W[(size_t)(k0 + kk) * nout + cc2];
            }
            wT[kk][c] = v;
        }
        __syncthreads();
        #pragma unroll
        for (int kk = 0; kk < 16; ++kk) {
            float a[4], b[4];
            #pragma unroll
            for (int r = 0; r < 4; ++r) a[r] = sT[tr * 4 + r][kk];
            #pragma unroll
            for (int c = 0; c < 4; ++c) b[c] = wT[kk][tc * 4 + c];
            #pragma unroll
            for (int r = 0; r < 4; ++r)
                #pragma unroll
                for (int c = 0; c < 4; ++c) acc[r][c] += a[r] * b[c];
        }
    }
    for (int r = 0; r < 4; ++r)
        for (int c = 0; c < 4; ++c) {
            int col = n0 + tc * 4 + c;
            if (col < NLIN)
                lin[(size_t)(i0 + tr * 4 + r) * NLIN + col] = acc[r][c];
        }
}

// ---------------------------------------------------------------------------
// Kernel 2: transforms -> hi/lo bf16 bundles (h-major), vT pack (v1+v3g),
// fp32 sqwh/skwh (h-major), Wz A-frag pack.
// ---------------------------------------------------------------------------
__global__ __launch_bounds__(192) void transform_kernel(
    const float* __restrict__ lin, const float* __restrict__ rot,
    const float* __restrict__ trans, const float* __restrict__ gamma,
    const float* __restrict__ Wz,
    ushort* __restrict__ vT,
    ushort* __restrict__ qbh, ushort* __restrict__ qbl,
    ushort* __restrict__ kbh, ushort* __restrict__ kbl,
    ushort* __restrict__ wzpack,
    float* __restrict__ sqwh, float* __restrict__ skwh)
{
    const int l = blockIdx.x;
    const int tid = threadIdx.x;
    __shared__ float q2s[144], k2s[144], sqp[48], skp[48];
    __shared__ float v3s[216];
    __shared__ float whs[12];
    __shared__ float R[9], T[3];
    if (tid < 9) R[tid] = rot[l * 9 + tid];
    if (tid >= 9 && tid < 12) T[tid - 9] = trans[l * 3 + tid - 9];
    __syncthreads();
    if (tid < 48) {
        const float* x = &lin[(size_t)l * NLIN + 576 + tid * 3];
        float x0 = x[0], x1 = x[1], x2 = x[2], ss = 0.f;
        #pragma unroll
        for (int i2 = 0; i2 < 3; ++i2) {
            float v = R[i2*3+0]*x0 + R[i2*3+1]*x1 + R[i2*3+2]*x2 + T[i2];
            q2s[tid * 3 + i2] = v; ss += v * v;
        }
        sqp[tid] = ss;
    } else if (tid < 96) {
        int t2 = tid - 48;
        const float* x = &lin[(size_t)l * NLIN + 720 + t2 * 3];
        float x0 = x[0], x1 = x[1], x2 = x[2], ss = 0.f;
        #pragma unroll
        for (int i2 = 0; i2 < 3; ++i2) {
            float v = R[i2*3+0]*x0 + R[i2*3+1]*x1 + R[i2*3+2]*x2 + T[i2];
            k2s[t2 * 3 + i2] = v; ss += v * v;
        }
        skp[t2] = ss;
    } else if (tid < 168) {
        int t2 = tid - 96;
        const float* x = &lin[(size_t)l * NLIN + 864 + t2 * 3];
        float x0 = x[0], x1 = x[1], x2 = x[2];
        #pragma unroll
        for (int i2 = 0; i2 < 3; ++i2) {
            float v = R[i2*3+0]*x0 + R[i2*3+1]*x1 + R[i2*3+2]*x2 + T[i2];
            v3s[t2 * 3 + i2] = v;   // [h*18 + p*3 + t]
        }
    }
    __syncthreads();
    if (tid < 12) {
        float sq = sqp[tid*4] + sqp[tid*4+1] + sqp[tid*4+2] + sqp[tid*4+3];
        float sk = skp[tid*4] + skp[tid*4+1] + skp[tid*4+2] + skp[tid*4+3];
        float w = logf(1.0f + expf(gamma[tid])) * WC_HALF;
        whs[tid] = w;
        sqwh[tid * 768 + l] = w * sq;   // [h][l], fp32 exact path
        skwh[tid * 768 + l] = w * sk;
    }
    __syncthreads();
    // vT[h][c][j=l]: c 0-15 = v1 (lin 384 + h*16 + c), c 16-33 = v3g idx c-16
    for (int w = tid; w < 408; w += 192) {
        int h = w / 34, c = w % 34;
        float v = (c < 16) ? lin[(size_t)l * NLIN + 384 + h * 16 + c]
                           : v3s[h * 18 + (c - 16)];
        vT[((size_t)h * 48 + c) * 768 + l] = f2bu(v);
    }
    for (int idx = tid; idx < 384; idx += 192) {
        int h = idx >> 5, k = idx & 31;
        float qv, kv;
        if (k < 16) {
            qv = lin[(size_t)l * NLIN + h * 16 + k];
            kv = C_SQU * lin[(size_t)l * NLIN + 192 + h * 16 + k];
        } else if (k < 28) {
            int u = k - 16;
            qv = q2s[h * 12 + u];
            kv = 2.0f * whs[h] * k2s[h * 12 + u];
        } else { qv = 0.0f; kv = 0.0f; }
        size_t base = ((size_t)h * 768 + l) * 32 + k;   // h-major
        ushort qh = f2bu(qv), kh = f2bu(kv);
        qbh[base] = qh; qbl[base] = f2bu(qv - bu2f(qh));
        kbh[base] = kh; kbl[base] = f2bu(kv - bu2f(kh));
    }
    if (l == 0) {  // wzpack[kb][lane][e] = Wz[kb*32+(lane>>4)*8+e][lane&15]
        for (int idx = tid; idx < 2048; idx += 192) {
            int kb = idx >> 9, lane = (idx >> 3) & 63, e = idx & 7;
            int d = kb * 32 + (lane >> 4) * 8 + e, h = lane & 15;
            wzpack[idx] = (h < 12) ? f2bu(Wz[d * 12 + h]) : (ushort)0;
        }
    }
}

// ---------------------------------------------------------------------------
// Kernel 3: sx[i][h][j] = hi/lo-dot(qb,kb) - sqwh[h,i] - skwh[h,j] (fp32)
// h fully grid-parallel: grid (48 i, 12 jb, 12 h).
// ---------------------------------------------------------------------------
__global__ __launch_bounds__(256) void sextra_kernel(
    const ushort* __restrict__ qbh, const ushort* __restrict__ qbl,
    const ushort* __restrict__ kbh, const ushort* __restrict__ kbl,
    const float* __restrict__ sqwh, const float* __restrict__ skwh,
    float* __restrict__ sx)
{
    const int tid = threadIdx.x;
    const int wv = tid >> 6, lane = tid & 63, lm = lane & 15, g = lane >> 4;
    const int i0 = blockIdx.x * 16;
    const int jb = blockIdx.y * 64 + wv * 16;
    const int h = blockIdx.z;
    size_t qoff = ((size_t)h * 768 + i0 + lm) * 32 + g * 8;
    size_t koff = ((size_t)h * 768 + jb + lm) * 32 + g * 8;
    short8v ah = *(const short8v*)(qbh + qoff);
    short8v al = *(const short8v*)(qbl + qoff);
    short8v bh = *(const short8v*)(kbh + koff);
    short8v bl = *(const short8v*)(kbl + koff);
    float4v c1 = {0.f, 0.f, 0.f, 0.f};
    float4v c2 = {0.f, 0.f, 0.f, 0.f};
    c1 = __builtin_amdgcn_mfma_f32_16x16x32_bf16(ah, bh, c1, 0, 0, 0);
    c2 = __builtin_amdgcn_mfma_f32_16x16x32_bf16(ah, bl, c2, 0, 0, 0);
    c2 = __builtin_amdgcn_mfma_f32_16x16x32_bf16(al, bh, c2, 0, 0, 0);
    float skv = skwh[h * 768 + jb + lm];
    #pragma unroll
    for (int r = 0; r < 4; ++r) {
        int ii = i0 + g * 4 + r;
        sx[((size_t)ii * 12 + h) * 768 + jb + lm] =
            (c1[r] + c2[r]) - sqwh[h * 768 + ii] - skv;
    }
}

// ---------------------------------------------------------------------------
// Kernel 4: attention A = bias + o1. 1 block/row, 12 JT=64 tiles (R18
// structure minus the row split; no setprio). Writes o1 directly.
// Barrier order: phaseA | bar | phaseB; STAGE | bar.
// ---------------------------------------------------------------------------
__global__ __launch_bounds__(256) void attn_kernel(
    const float* __restrict__ z, const ushort* __restrict__ wzp,
    float* sxa,                 // in: scores; out: att (same buffer)
    float* __restrict__ o1)
{
    const int i = blockIdx.x, tid = threadIdx.x;
    const int wv = tid >> 6, lane = tid & 63, lm = lane & 15, g = lane >> 4;
    __shared__ __attribute__((aligned(16))) char zrow[2][64 * 256]; // [j][d] bf16, swz fswz(j)
    __shared__ __attribute__((aligned(16))) char attbh[16 * 144];   // hi bf16 [h][64j], stride 144B
    __shared__ __attribute__((aligned(16))) char attbl[16 * 144];   // lo bf16

    short8v wzf[4];
    #pragma unroll
    for (int kb = 0; kb < 4; ++kb)
        wzf[kb] = *(const short8v*)(wzp + (kb * 64 + lane) * 8);

    const float4* zsrc = (const float4*)(z + (size_t)i * (LL * 128));
    const int jA = wv * 16 + lm;   // phase-A j: ALL 4 waves active (j 0..63)

    // prologue: tile 0 (64 j x 128 d)
    {
        float4 z0[8];
        #pragma unroll
        for (int s = 0; s < 8; ++s) z0[s] = zsrc[s * 256 + tid];
        #pragma unroll
        for (int s = 0; s < 8; ++s) {
            int k4 = s * 256 + tid, j = k4 >> 5, d0 = (k4 & 31) * 4;
            float4 v = z0[s];
            ushort b0 = f2bu(v.x), b1 = f2bu(v.y), b2 = f2bu(v.z), b3 = f2bu(v.w);
            uint32_t lo = b0 | ((uint32_t)b1 << 16), hi = b2 | ((uint32_t)b3 << 16);
            *(uint64_t*)(&zrow[0][j * 256 + ((d0 * 2) ^ fswz(j))]) =
                (uint64_t)lo | ((uint64_t)hi << 32);
        }
    }
    float sxr[4] = {0.f, 0.f, 0.f, 0.f};
    if (g < 3) {
        #pragma unroll
        for (int r = 0; r < 4; ++r)
            sxr[r] = sxa[((size_t)i * 12 + g * 4 + r) * 768 + jA];
    }
    __syncthreads();

    float4v acc1[2] = {{0.f,0.f,0.f,0.f}, {0.f,0.f,0.f,0.f}};
    int p = 0;

    for (int t = 0; t < 12; ++t) {
        const int j0 = t * 64;
        float4 zreg[8];
        if (t < 11) {
            #pragma unroll
            for (int s = 0; s < 8; ++s)
                zreg[s] = zsrc[(size_t)(t + 1) * 2048 + s * 256 + tid];
        }
        float sxn[4] = {0.f, 0.f, 0.f, 0.f};
        if (g < 3 && t < 11) {
            #pragma unroll
            for (int r = 0; r < 4; ++r)
                sxn[r] = sxa[((size_t)i * 12 + g * 4 + r) * 768 + j0 + 64 + jA];
        }
        // phase A (4-wave): bias MFMA for this wave's 16-j strip
        {
            float4v bias = {0.f, 0.f, 0.f, 0.f};
            #pragma unroll
            for (int kb = 0; kb < 4; ++kb) {
                short8v bz = *(const short8v*)(
                    &zrow[p][jA * 256 + ((kb * 64 + g * 16) ^ fswz(jA))]);
                bias = __builtin_amdgcn_mfma_f32_16x16x32_bf16(wzf[kb], bz, bias, 0, 0, 0);
            }
            #pragma unroll
            for (int r = 0; r < 4; ++r) {
                int h = g * 4 + r;
                float att = bias[r] + sxr[r];
                ushort hi = f2bu(att);
                *(ushort*)(&attbh[h * 144 + jA * 2]) = hi;
                *(ushort*)(&attbl[h * 144 + jA * 2]) = f2bu(att - bu2f(hi));
                if (g < 3)
                    sxa[((size_t)i * 12 + h) * 768 + j0 + jA] = att;
            }
        }
        __syncthreads();
        // phase B: o1 MFMA over 64 j (2 K-steps), B-frags via column b16 reads
        #pragma unroll
        for (int ks = 0; ks < 2; ++ks) {
            short8v ah = *(const short8v*)(&attbh[lm * 144 + ks * 64 + g * 16]);
            short8v al = *(const short8v*)(&attbl[lm * 144 + ks * 64 + g * 16]);
            #pragma unroll
            for (int q = 0; q < 2; ++q) {
                const int b = wv * 2 + q;
                short8v bf;
                #pragma unroll
                for (int e = 0; e < 8; ++e) {
                    int jj = ks * 32 + g * 8 + e;
                    bf[e] = *(const short*)(&zrow[p][jj * 256 +
                              (((b * 16 + lm) * 2) ^ fswz(jj))]);
                }
                acc1[q] = __builtin_amdgcn_mfma_f32_16x16x32_bf16(ah, bf, acc1[q], 0, 0, 0);
                acc1[q] = __builtin_amdgcn_mfma_f32_16x16x32_bf16(al, bf, acc1[q], 0, 0, 0);
            }
        }
        // STAGE next tile (vmcnt drain lands after phase B MFMAs issue)
        if (t < 11) {
            #pragma unroll
            for (int s = 0; s < 8; ++s) {
                int k4 = s * 256 + tid, j = k4 >> 5, d0 = (k4 & 31) * 4;
                float4 v = zreg[s];
                ushort b0 = f2bu(v.x), b1 = f2bu(v.y), b2 = f2bu(v.z), b3 = f2bu(v.w);
                uint32_t lo = b0 | ((uint32_t)b1 << 16), hi = b2 | ((uint32_t)b3 << 16);
                *(uint64_t*)(&zrow[p ^ 1][j * 256 + ((d0 * 2) ^ fswz(j))]) =
                    (uint64_t)lo | ((uint64_t)hi << 32);
            }
        }
        __syncthreads();
        #pragma unroll
        for (int r = 0; r < 4; ++r) sxr[r] = sxn[r];
        p ^= 1;
    }
    if (g < 3) {
        #pragma unroll
        for (int q = 0; q < 2; ++q) {
            const int b = wv * 2 + q;
            #pragma unroll
            for (int r = 0; r < 4; ++r)
                o1[(size_t)i * 1536 + (g * 4 + r) * 128 + b * 16 + lm] = acc1[q][r];
        }
    }
}

// ---------------------------------------------------------------------------
// Kernel 5: ov = o2 + o3 via MFMA over materialized att.
// grid (48 i-tiles, 12 h), 256 threads: 4 waves K-split + LDS reduce.
// ---------------------------------------------------------------------------
__global__ __launch_bounds__(256) void ov_kernel(
    const float* __restrict__ att, const ushort* __restrict__ vT,
    const float* __restrict__ rot, const float* __restrict__ trans,
    float* __restrict__ o2, float* __restrict__ o3l)
{
    const int i0 = blockIdx.x * 16;
    const int h = blockIdx.y;
    const int tid = threadIdx.x;
    const int wv = tid >> 6, lane = tid & 63;
    const int lm = lane & 15, g = lane >> 4;
    __shared__ float red[4][3][64][4];
    __shared__ float o3s[16][18];

    float4v acc0 = {0.f,0.f,0.f,0.f};
    float4v acc1 = {0.f,0.f,0.f,0.f};
    float4v acc2 = {0.f,0.f,0.f,0.f};
    const float* arow = att + ((size_t)(i0 + lm) * 12 + h) * 768;
    const ushort* vbase = vT + (size_t)h * 48 * 768;
    for (int kt = wv; kt < 24; kt += 4) {
        const float4* ap = (const float4*)(arow + kt * 32 + g * 8);
        float4 a0 = ap[0], a1 = ap[1];
        float av[8] = {a0.x, a0.y, a0.z, a0.w, a1.x, a1.y, a1.z, a1.w};
        short8v ah, al;
        #pragma unroll
        for (int e = 0; e < 8; ++e) {
            ushort hi = f2bu(av[e]);
            ah[e] = (short)hi;
            al[e] = (short)f2bu(av[e] - bu2f(hi));
        }
        const int kq = kt * 32 + g * 8;
        short8v b0 = *(const short8v*)(vbase + (size_t)(0 * 16 + lm) * 768 + kq);
        short8v b1 = *(const short8v*)(vbase + (size_t)(1 * 16 + lm) * 768 + kq);
        short8v b2 = *(const short8v*)(vbase + (size_t)(2 * 16 + lm) * 768 + kq);
        acc0 = __builtin_amdgcn_mfma_f32_16x16x32_bf16(ah, b0, acc0, 0, 0, 0);
        acc0 = __builtin_amdgcn_mfma_f32_16x16x32_bf16(al, b0, acc0, 0, 0, 0);
        acc1 = __builtin_amdgcn_mfma_f32_16x16x32_bf16(ah, b1, acc1, 0, 0, 0);
        acc1 = __builtin_amdgcn_mfma_f32_16x16x32_bf16(al, b1, acc1, 0, 0, 0);
        acc2 = __builtin_amdgcn_mfma_f32_16x16x32_bf16(ah, b2, acc2, 0, 0, 0);
        acc2 = __builtin_amdgcn_mfma_f32_16x16x32_bf16(al, b2, acc2, 0, 0, 0);
    }
    #pragma unroll
    for (int r = 0; r < 4; ++r) {
        red[wv][0][lane][r] = acc0[r];
        red[wv][1][lane][r] = acc1[r];
        red[wv][2][lane][r] = acc2[r];
    }
    __syncthreads();
    for (int v = tid; v < 768; v += 256) {
        int a = v >> 8, rem = v & 255;
        int l2 = rem >> 2, r = rem & 3;
        float sum = red[0][a][l2][r] + red[1][a][l2][r]
                  + red[2][a][l2][r] + red[3][a][l2][r];
        int lm2 = l2 & 15, g2 = l2 >> 4;
        int row = g2 * 4 + r;
        if (a == 0)      o2[(size_t)(i0 + row) * 192 + h * 16 + lm2] = sum;
        else if (a == 1) o3s[row][lm2] = sum;
        else if (lm2 < 2) o3s[row][16 + lm2] = sum;
    }
    __syncthreads();
    for (int it = tid; it < 96; it += 256) {
        int row = it / 6, pp = it % 6;
        int ii = i0 + row;
        const float* R = &rot[(size_t)ii * 9];
        float x0 = o3s[row][pp * 3 + 0] - trans[ii * 3 + 0];
        float x1 = o3s[row][pp * 3 + 1] - trans[ii * 3 + 1];
        float x2 = o3s[row][pp * 3 + 2] - trans[ii * 3 + 2];
        o3l[(size_t)ii * 216 + h * 18 + pp * 3 + 0] = R[0]*x0 + R[3]*x1 + R[6]*x2;
        o3l[(size_t)ii * 216 + h * 18 + pp * 3 + 1] = R[1]*x0 + R[4]*x1 + R[7]*x2;
        o3l[(size_t)ii * 216 + h * 18 + pp * 3 + 2] = R[2]*x0 + R[5]*x1 + R[8]*x2;
    }
}

// ---------------------------------------------------------------------------
// Kernel 6: partial output projection, grid-parallel (48 it x 6 kt = 288
// blocks). Reads o1 directly. part[] -> final_kernel.
// ---------------------------------------------------------------------------
#define KCH 324
__global__ __launch_bounds__(384) void proj_kernel(
    const float* __restrict__ o1, const float* __restrict__ o2,
    const float* __restrict__ o3l,
    const float* __restrict__ W1, const float* __restrict__ W2,
    const float* __restrict__ W3,
    float* __restrict__ part)
{
    const int it = blockIdx.x, kt = blockIdx.y;
    const int tid = threadIdx.x;
    const int kbeg = kt * KCH, kend = kbeg + KCH;
    __shared__ float olds[16][KCH];
    for (int idx = tid; idx < 16 * KCH; idx += 384) {
        int r = idx / KCH, kk = idx % KCH;
        int k = kbeg + kk;
        int i = it * 16 + r;
        float v;
        if (k < 1536)      v = o1[(size_t)i * 1536 + k];
        else if (k < 1728) v = o2[(size_t)i * 192 + k - 1536];
        else               v = o3l[(size_t)i * 216 + k - 1728];
        olds[r][kk] = v;
    }
    __syncthreads();
    float acc[16] = {};
    {
        int s0 = kbeg, s1 = (kend < 1536) ? kend : 1536;
        for (int k = s0; k < s1; ++k) {
            float w = W1[(size_t)k * 384 + tid];
            int kk = k - kbeg;
            #pragma unroll
            for (int r = 0; r < 16; ++r) acc[r] += olds[r][kk] * w;
        }
    }
    {
        int s0 = (kbeg > 1536) ? kbeg : 1536, s1 = (kend < 1728) ? kend : 1728;
        for (int k = s0; k < s1; ++k) {
            float w = W2[(size_t)(k - 1536) * 384 + tid];
            int kk = k - kbeg;
            #pragma unroll
            for (int r = 0; r < 16; ++r) acc[r] += olds[r][kk] * w;
        }
    }
    {
        int s0 = (kbeg > 1728) ? kbeg : 1728, s1 = kend;
        for (int k = s0; k < s1; ++k) {
            float w = W3[(size_t)(k - 1728) * 384 + tid];
            int kk = k - kbeg;
            #pragma unroll
            for (int r = 0; r < 16; ++r) acc[r] += olds[r][kk] * w;
        }
    }
    for (int r = 0; r < 16; ++r)
        part[((size_t)kt * LL + it * 16 + r) * 384 + tid] = acc[r];
}

// ---------------------------------------------------------------------------
// Kernel 7: reduce partials + biases
// ---------------------------------------------------------------------------
__global__ __launch_bounds__(256) void final_kernel(
    const float* __restrict__ part,
    const float* __restrict__ b1, const float* __restrict__ b2,
    const float* __restrict__ b3, float* __restrict__ out)
{
    int idx = blockIdx.x * 256 + threadIdx.x;
    if (idx < LL * 384) {
        int n = idx % 384;
        float v = b1[n] + b2[n] + b3[n];
        #pragma unroll
        for (int kt = 0; kt < 6; ++kt) v += part[(size_t)kt * 294912 + idx];
        out[idx] = v;
    }
}

extern "C" void kernel_launch(void* const* d_in, const int* in_sizes, int n_in,
                              void* d_out, int out_size, void* d_ws, size_t ws_size,
                              hipStream_t stream) {
    const float* s     = (const float*)d_in[0];
    const float* z     = (const float*)d_in[1];
    const float* rot   = (const float*)d_in[2];
    const float* trans = (const float*)d_in[3];
    const float* Wq1   = (const float*)d_in[4];
    const float* Wk1   = (const float*)d_in[5];
    const float* Wv1   = (const float*)d_in[6];
    const float* Wq2   = (const float*)d_in[7];
    const float* Wk2   = (const float*)d_in[8];
    const float* Wv3   = (const float*)d_in[9];
    const float* Wz    = (const float*)d_in[10];
    const float* W1    = (const float*)d_in[11];
    const float* b1    = (const float*)d_in[12];
    const float* W2    = (const float*)d_in[13];
    const float* b2    = (const float*)d_in[14];
    const float* W3    = (const float*)d_in[15];
    const float* b3    = (const float*)d_in[16];
    const float* gamma = (const float*)d_in[17];
    float* ws  = (float*)d_ws;
    float* out = (float*)d_out;

    float*  lin  = ws + OFF_LIN;
    ushort* vT   = (ushort*)(ws + OFF_VT);
    ushort* qbh  = (ushort*)(ws + OFF_QBH);
    ushort* qbl  = (ushort*)(ws + OFF_QBL);
    ushort* kbh  = (ushort*)(ws + OFF_KBH);
    ushort* kbl  = (ushort*)(ws + OFF_KBL);
    ushort* wzp  = (ushort*)(ws + OFF_WZ);
    float*  sqwh = ws + OFF_SQWH;
    float*  skwh = ws + OFF_SKWH;
    float*  sx   = ws + OFF_SX;     // scores -> att (in-place) -> dead after ov
    float*  o2   = ws + OFF_O2;
    float*  o3l  = ws + OFF_O3;
    float*  o1   = ws + OFF_O1;
    float*  part = ws + OFF_SX;     // alias: att dead before proj runs

    dim3 gA(17, 12);
    gemm_lin_kernel<<<gA, 256, 0, stream>>>(s, Wq1, Wk1, Wv1, Wq2, Wk2, Wv3, lin);
    transform_kernel<<<LL, 192, 0, stream>>>(lin, rot, trans, gamma, Wz,
                                             vT, qbh, qbl, kbh, kbl, wzp,
                                             sqwh, skwh);
    dim3 gS(48, 12, 12);
    sextra_kernel<<<gS, 256, 0, stream>>>(qbh, qbl, kbh, kbl, sqwh, skwh, sx);
    attn_kernel<<<LL, 256, 0, stream>>>(z, wzp, sx, o1);
    dim3 gV(48, 12);
    ov_kernel<<<gV, 256, 0, stream>>>(sx, vT, rot, trans, o2, o3l);
    dim3 gC(48, 6);
    proj_kernel<<<gC, 384, 0, stream>>>(o1, o2, o3l, W1, W2, W3, part);
    final_kernel<<<(LL * 384 + 255) / 256, 256, 0, stream>>>(part, b1, b2, b3, out);
}

// Round 21
// 271.074 us; speedup vs baseline: 1.0330x; 1.0330x over previous
//
#include <hip/hip_runtime.h>
#include <math.h>
#include <stdint.h>

// Problem constants
#define LL 768
#define DIN 384
#define HH 12
#define NLIN 1080          // 192*3 + 144*2 + 216
#define WC_HALF 0.11785113019775792f   // 0.5*sqrt(2/36)
#define C_SQU 0.25f

// Workspace layout (float units)
#define OFF_LIN    0u          // 829440
#define OFF_VT     829440u     // 221184 (ushort [12][48][768]: c0-15=v1, 16-33=v3g)
#define OFF_QBH    1050624u    // 147456 (bf16 [12][768][32])
#define OFF_QBL    1198080u    // 147456
#define OFF_KBH    1345536u    // 147456
#define OFF_KBL    1492992u    // 147456
#define OFF_WZ     1640448u    // 1024   (bf16 4*64*8)
#define OFF_SQWH   1641472u    // 9216   ([12][768])
#define OFF_SKWH   1650688u    // 9216
#define OFF_SX     1659904u    // 7077888 fp32 scores; attn overwrites in-place with att;
                               //          proj's part[] aliases here after ov consumes att
#define OFF_O2     8737792u    // 147456
#define OFF_O3     8885248u    // 165888
#define OFF_PO1    9051136u    // 2359296 (2 halves x 768 x 1536)
// end: 11410432 floats = 45.6 MB

typedef __attribute__((ext_vector_type(8))) short short8v;
typedef __attribute__((ext_vector_type(4))) float float4v;

__device__ __forceinline__ ushort f2bu(float f) {
    union { float f; uint32_t u; } v; v.f = f;
    uint32_t r = (v.u + 0x7FFFu + ((v.u >> 16) & 1u)) >> 16;
    return (ushort)r;
}
__device__ __forceinline__ float bu2f(ushort u) {
    union { uint32_t u; float f; } v; v.u = ((uint32_t)u) << 16; return v.f;
}
// LDS row swizzle: bijective within each 256-B row for j in [0,64).
__device__ __forceinline__ int fswz(int j) {
    return (((j >> 3) << 1) | ((j >> 1) & 1)) << 4;
}

// ---------------------------------------------------------------------------
// Kernel 1: lin = s @ [Wq1|Wk1|Wv1|Wq2|Wk2|Wv3]   ([768,384]@[384,1080])
// ---------------------------------------------------------------------------
__global__ __launch_bounds__(256) void gemm_lin_kernel(
    const float* __restrict__ s,
    const float* __restrict__ Wq1, const float* __restrict__ Wk1,
    const float* __restrict__ Wv1, const float* __restrict__ Wq2,
    const float* __restrict__ Wk2, const float* __restrict__ Wv3,
    float* __restrict__ lin)
{
    const int n0 = blockIdx.x * 64;
    const int i0 = blockIdx.y * 64;
    const int tid = threadIdx.x;
    __shared__ float sT[64][17];
    __shared__ float wT[16][65];
    const int tc = tid & 15, tr = tid >> 4;
    float acc[4][4] = {};
    for (int k0 = 0; k0 < DIN; k0 += 16) {
        __syncthreads();
        for (int idx = tid; idx < 1024; idx += 256) {
            int r = idx >> 4, kk = idx & 15;
            sT[r][kk] = s[(size_t)(i0 + r) * DIN + k0 + kk];
        }
        for (int idx = tid; idx < 1024; idx += 256) {
            int kk = idx >> 6, c = idx & 63;
            int col = n0 + c;
            float v = 0.f;
            if (col < NLIN) {
                const float* W; int nout, cc2;
                if      (col < 192) { W = Wq1; nout = 192; cc2 = col; }
                else if (col < 384) { W = Wk1; nout = 192; cc2 = col - 192; }
                else if (col < 576) { W = Wv1; nout = 192; cc2 = col - 384; }
                else if (col < 720) { W = Wq2; nout = 144; cc2 = col - 576; }
                else if (col < 864) { W = Wk2; nout = 144; cc2 = col - 720; }
                else                { W = Wv3; nout = 216; cc2 = col - 864; }
                v = W[(size_t)(k0 + kk) * nout + cc2];
            }
            wT[kk][c] = v;
        }
        __syncthreads();
        #pragma unroll
        for (int kk = 0; kk < 16; ++kk) {
            float a[4], b[4];
            #pragma unroll
            for (int r = 0; r < 4; ++r) a[r] = sT[tr * 4 + r][kk];
            #pragma unroll
            for (int c = 0; c < 4; ++c) b[c] = wT[kk][tc * 4 + c];
            #pragma unroll
            for (int r = 0; r < 4; ++r)
                #pragma unroll
                for (int c = 0; c < 4; ++c) acc[r][c] += a[r] * b[c];
        }
    }
    for (int r = 0; r < 4; ++r)
        for (int c = 0; c < 4; ++c) {
            int col = n0 + tc * 4 + c;
            if (col < NLIN)
                lin[(size_t)(i0 + tr * 4 + r) * NLIN + col] = acc[r][c];
        }
}

// ---------------------------------------------------------------------------
// Kernel 2: transforms -> hi/lo bf16 bundles (h-major), vT pack (v1+v3g),
// fp32 sqwh/skwh (h-major), Wz A-frag pack.
// ---------------------------------------------------------------------------
__global__ __launch_bounds__(192) void transform_kernel(
    const float* __restrict__ lin, const float* __restrict__ rot,
    const float* __restrict__ trans, const float* __restrict__ gamma,
    const float* __restrict__ Wz,
    ushort* __restrict__ vT,
    ushort* __restrict__ qbh, ushort* __restrict__ qbl,
    ushort* __restrict__ kbh, ushort* __restrict__ kbl,
    ushort* __restrict__ wzpack,
    float* __restrict__ sqwh, float* __restrict__ skwh)
{
    const int l = blockIdx.x;
    const int tid = threadIdx.x;
    __shared__ float q2s[144], k2s[144], sqp[48], skp[48];
    __shared__ float v3s[216];
    __shared__ float whs[12];
    __shared__ float R[9], T[3];
    if (tid < 9) R[tid] = rot[l * 9 + tid];
    if (tid >= 9 && tid < 12) T[tid - 9] = trans[l * 3 + tid - 9];
    __syncthreads();
    if (tid < 48) {
        const float* x = &lin[(size_t)l * NLIN + 576 + tid * 3];
        float x0 = x[0], x1 = x[1], x2 = x[2], ss = 0.f;
        #pragma unroll
        for (int i2 = 0; i2 < 3; ++i2) {
            float v = R[i2*3+0]*x0 + R[i2*3+1]*x1 + R[i2*3+2]*x2 + T[i2];
            q2s[tid * 3 + i2] = v; ss += v * v;
        }
        sqp[tid] = ss;
    } else if (tid < 96) {
        int t2 = tid - 48;
        const float* x = &lin[(size_t)l * NLIN + 720 + t2 * 3];
        float x0 = x[0], x1 = x[1], x2 = x[2], ss = 0.f;
        #pragma unroll
        for (int i2 = 0; i2 < 3; ++i2) {
            float v = R[i2*3+0]*x0 + R[i2*3+1]*x1 + R[i2*3+2]*x2 + T[i2];
            k2s[t2 * 3 + i2] = v; ss += v * v;
        }
        skp[t2] = ss;
    } else if (tid < 168) {
        int t2 = tid - 96;
        const float* x = &lin[(size_t)l * NLIN + 864 + t2 * 3];
        float x0 = x[0], x1 = x[1], x2 = x[2];
        #pragma unroll
        for (int i2 = 0; i2 < 3; ++i2) {
            float v = R[i2*3+0]*x0 + R[i2*3+1]*x1 + R[i2*3+2]*x2 + T[i2];
            v3s[t2 * 3 + i2] = v;   // [h*18 + p*3 + t]
        }
    }
    __syncthreads();
    if (tid < 12) {
        float sq = sqp[tid*4] + sqp[tid*4+1] + sqp[tid*4+2] + sqp[tid*4+3];
        float sk = skp[tid*4] + skp[tid*4+1] + skp[tid*4+2] + skp[tid*4+3];
        float w = logf(1.0f + expf(gamma[tid])) * WC_HALF;
        whs[tid] = w;
        sqwh[tid * 768 + l] = w * sq;   // [h][l], fp32 exact path
        skwh[tid * 768 + l] = w * sk;
    }
    __syncthreads();
    // vT[h][c][j=l]: c 0-15 = v1 (lin 384 + h*16 + c), c 16-33 = v3g idx c-16
    for (int w = tid; w < 408; w += 192) {
        int h = w / 34, c = w % 34;
        float v = (c < 16) ? lin[(size_t)l * NLIN + 384 + h * 16 + c]
                           : v3s[h * 18 + (c - 16)];
        vT[((size_t)h * 48 + c) * 768 + l] = f2bu(v);
    }
    for (int idx = tid; idx < 384; idx += 192) {
        int h = idx >> 5, k = idx & 31;
        float qv, kv;
        if (k < 16) {
            qv = lin[(size_t)l * NLIN + h * 16 + k];
            kv = C_SQU * lin[(size_t)l * NLIN + 192 + h * 16 + k];
        } else if (k < 28) {
            int u = k - 16;
            qv = q2s[h * 12 + u];
            kv = 2.0f * whs[h] * k2s[h * 12 + u];
        } else { qv = 0.0f; kv = 0.0f; }
        size_t base = ((size_t)h * 768 + l) * 32 + k;   // h-major
        ushort qh = f2bu(qv), kh = f2bu(kv);
        qbh[base] = qh; qbl[base] = f2bu(qv - bu2f(qh));
        kbh[base] = kh; kbl[base] = f2bu(kv - bu2f(kh));
    }
    if (l == 0) {  // wzpack[kb][lane][e] = Wz[kb*32+(lane>>4)*8+e][lane&15]
        for (int idx = tid; idx < 2048; idx += 192) {
            int kb = idx >> 9, lane = (idx >> 3) & 63, e = idx & 7;
            int d = kb * 32 + (lane >> 4) * 8 + e, h = lane & 15;
            wzpack[idx] = (h < 12) ? f2bu(Wz[d * 12 + h]) : (ushort)0;
        }
    }
}

// ---------------------------------------------------------------------------
// Kernel 3: sx[i][h][j] = hi/lo-dot(qb,kb) - sqwh[h,i] - skwh[h,j] (fp32)
// h fully grid-parallel: grid (48 i, 12 jb, 12 h).
// ---------------------------------------------------------------------------
__global__ __launch_bounds__(256) void sextra_kernel(
    const ushort* __restrict__ qbh, const ushort* __restrict__ qbl,
    const ushort* __restrict__ kbh, const ushort* __restrict__ kbl,
    const float* __restrict__ sqwh, const float* __restrict__ skwh,
    float* __restrict__ sx)
{
    const int tid = threadIdx.x;
    const int wv = tid >> 6, lane = tid & 63, lm = lane & 15, g = lane >> 4;
    const int i0 = blockIdx.x * 16;
    const int jb = blockIdx.y * 64 + wv * 16;
    const int h = blockIdx.z;
    size_t qoff = ((size_t)h * 768 + i0 + lm) * 32 + g * 8;
    size_t koff = ((size_t)h * 768 + jb + lm) * 32 + g * 8;
    short8v ah = *(const short8v*)(qbh + qoff);
    short8v al = *(const short8v*)(qbl + qoff);
    short8v bh = *(const short8v*)(kbh + koff);
    short8v bl = *(const short8v*)(kbl + koff);
    float4v c1 = {0.f, 0.f, 0.f, 0.f};
    float4v c2 = {0.f, 0.f, 0.f, 0.f};
    c1 = __builtin_amdgcn_mfma_f32_16x16x32_bf16(ah, bh, c1, 0, 0, 0);
    c2 = __builtin_amdgcn_mfma_f32_16x16x32_bf16(ah, bl, c2, 0, 0, 0);
    c2 = __builtin_amdgcn_mfma_f32_16x16x32_bf16(al, bh, c2, 0, 0, 0);
    float skv = skwh[h * 768 + jb + lm];
    #pragma unroll
    for (int r = 0; r < 4; ++r) {
        int ii = i0 + g * 4 + r;
        sx[((size_t)ii * 12 + h) * 768 + jb + lm] =
            (c1[r] + c2[r]) - sqwh[h * 768 + ii] - skv;
    }
}

// ---------------------------------------------------------------------------
// Kernel 4: attention A = bias + o1. JT=64 j-tiles: 2 blocks/row x 6 tiles.
// Phase A is 4-wave (each wave owns a 16-j strip). Barrier order:
// phaseA | bar | phaseB; STAGE | bar. att written in-place into sx (fp32).
// ---------------------------------------------------------------------------
__global__ __launch_bounds__(256) void attn_kernel(
    const float* __restrict__ z, const ushort* __restrict__ wzp,
    float* sxa,                 // in: scores; out: att (same buffer)
    float* __restrict__ po1)
{
    const int bid = blockIdx.x, tid = threadIdx.x;
    const int i = bid >> 1, t0 = (bid & 1) * 6;
    const int wv = tid >> 6, lane = tid & 63, lm = lane & 15, g = lane >> 4;
    __shared__ __attribute__((aligned(16))) char zrow[2][64 * 256]; // [j][d] bf16, swz fswz(j)
    __shared__ __attribute__((aligned(16))) char attbh[16 * 144];   // hi bf16 [h][64j], stride 144B
    __shared__ __attribute__((aligned(16))) char attbl[16 * 144];   // lo bf16

    short8v wzf[4];
    #pragma unroll
    for (int kb = 0; kb < 4; ++kb)
        wzf[kb] = *(const short8v*)(wzp + (kb * 64 + lane) * 8);

    const float4* zsrc = (const float4*)(z + (size_t)i * (LL * 128));
    const int jA = wv * 16 + lm;   // phase-A j: ALL 4 waves active (j 0..63)

    // prologue: tile t0 (64 j x 128 d)
    {
        float4 z0[8];
        #pragma unroll
        for (int s = 0; s < 8; ++s) z0[s] = zsrc[(size_t)t0 * 2048 + s * 256 + tid];
        #pragma unroll
        for (int s = 0; s < 8; ++s) {
            int k4 = s * 256 + tid, j = k4 >> 5, d0 = (k4 & 31) * 4;
            float4 v = z0[s];
            ushort b0 = f2bu(v.x), b1 = f2bu(v.y), b2 = f2bu(v.z), b3 = f2bu(v.w);
            uint32_t lo = b0 | ((uint32_t)b1 << 16), hi = b2 | ((uint32_t)b3 << 16);
            *(uint64_t*)(&zrow[0][j * 256 + ((d0 * 2) ^ fswz(j))]) =
                (uint64_t)lo | ((uint64_t)hi << 32);
        }
    }
    float sxr[4] = {0.f, 0.f, 0.f, 0.f};
    if (g < 3) {
        #pragma unroll
        for (int r = 0; r < 4; ++r)
            sxr[r] = sxa[((size_t)i * 12 + g * 4 + r) * 768 + t0 * 64 + jA];
    }
    __syncthreads();

    float4v acc1[2] = {{0.f,0.f,0.f,0.f}, {0.f,0.f,0.f,0.f}};
    int p = 0;

    for (int t = 0; t < 6; ++t) {
        const int tt = t0 + t, j0 = tt * 64;
        float4 zreg[8];
        if (t < 5) {
            #pragma unroll
            for (int s = 0; s < 8; ++s)
                zreg[s] = zsrc[(size_t)(tt + 1) * 2048 + s * 256 + tid];
        }
        float sxn[4] = {0.f, 0.f, 0.f, 0.f};
        if (g < 3 && t < 5) {
            #pragma unroll
            for (int r = 0; r < 4; ++r)
                sxn[r] = sxa[((size_t)i * 12 + g * 4 + r) * 768 + j0 + 64 + jA];
        }
        // phase A (4-wave): bias MFMA for this wave's 16-j strip
        {
            float4v bias = {0.f, 0.f, 0.f, 0.f};
            #pragma unroll
            for (int kb = 0; kb < 4; ++kb) {
                short8v bz = *(const short8v*)(
                    &zrow[p][jA * 256 + ((kb * 64 + g * 16) ^ fswz(jA))]);
                bias = __builtin_amdgcn_mfma_f32_16x16x32_bf16(wzf[kb], bz, bias, 0, 0, 0);
            }
            #pragma unroll
            for (int r = 0; r < 4; ++r) {
                int h = g * 4 + r;
                float att = bias[r] + sxr[r];
                ushort hi = f2bu(att);
                *(ushort*)(&attbh[h * 144 + jA * 2]) = hi;
                *(ushort*)(&attbl[h * 144 + jA * 2]) = f2bu(att - bu2f(hi));
                if (g < 3)
                    sxa[((size_t)i * 12 + h) * 768 + j0 + jA] = att;
            }
        }
        __syncthreads();
        // phase B: o1 MFMA over 64 j (2 K-steps), B-frags via column b16 reads
        #pragma unroll
        for (int ks = 0; ks < 2; ++ks) {
            short8v ah = *(const short8v*)(&attbh[lm * 144 + ks * 64 + g * 16]);
            short8v al = *(const short8v*)(&attbl[lm * 144 + ks * 64 + g * 16]);
            #pragma unroll
            for (int q = 0; q < 2; ++q) {
                const int b = wv * 2 + q;
                short8v bf;
                #pragma unroll
                for (int e = 0; e < 8; ++e) {
                    int jj = ks * 32 + g * 8 + e;
                    bf[e] = *(const short*)(&zrow[p][jj * 256 +
                              (((b * 16 + lm) * 2) ^ fswz(jj))]);
                }
                acc1[q] = __builtin_amdgcn_mfma_f32_16x16x32_bf16(ah, bf, acc1[q], 0, 0, 0);
                acc1[q] = __builtin_amdgcn_mfma_f32_16x16x32_bf16(al, bf, acc1[q], 0, 0, 0);
            }
        }
        // STAGE next tile (vmcnt drain lands after phase B MFMAs issue)
        if (t < 5) {
            #pragma unroll
            for (int s = 0; s < 8; ++s) {
                int k4 = s * 256 + tid, j = k4 >> 5, d0 = (k4 & 31) * 4;
                float4 v = zreg[s];
                ushort b0 = f2bu(v.x), b1 = f2bu(v.y), b2 = f2bu(v.z), b3 = f2bu(v.w);
                uint32_t lo = b0 | ((uint32_t)b1 << 16), hi = b2 | ((uint32_t)b3 << 16);
                *(uint64_t*)(&zrow[p ^ 1][j * 256 + ((d0 * 2) ^ fswz(j))]) =
                    (uint64_t)lo | ((uint64_t)hi << 32);
            }
        }
        __syncthreads();
        #pragma unroll
        for (int r = 0; r < 4; ++r) sxr[r] = sxn[r];
        p ^= 1;
    }
    if (g < 3) {
        #pragma unroll
        for (int q = 0; q < 2; ++q) {
            const int b = wv * 2 + q;
            #pragma unroll
            for (int r = 0; r < 4; ++r)
                po1[(size_t)bid * 1536 + (g * 4 + r) * 128 + b * 16 + lm] = acc1[q][r];
        }
    }
}

// ---------------------------------------------------------------------------
// Kernel 5: ov = o2 + o3 via MFMA over materialized att.
// grid (48 i-tiles, 12 h), 256 threads: 4 waves K-split + LDS reduce.
// ---------------------------------------------------------------------------
__global__ __launch_bounds__(256) void ov_kernel(
    const float* __restrict__ att, const ushort* __restrict__ vT,
    const float* __restrict__ rot, const float* __restrict__ trans,
    float* __restrict__ o2, float* __restrict__ o3l)
{
    const int i0 = blockIdx.x * 16;
    const int h = blockIdx.y;
    const int tid = threadIdx.x;
    const int wv = tid >> 6, lane = tid & 63;
    const int lm = lane & 15, g = lane >> 4;
    __shared__ float red[4][3][64][4];
    __shared__ float o3s[16][18];

    float4v acc0 = {0.f,0.f,0.f,0.f};
    float4v acc1 = {0.f,0.f,0.f,0.f};
    float4v acc2 = {0.f,0.f,0.f,0.f};
    const float* arow = att + ((size_t)(i0 + lm) * 12 + h) * 768;
    const ushort* vbase = vT + (size_t)h * 48 * 768;
    for (int kt = wv; kt < 24; kt += 4) {
        const float4* ap = (const float4*)(arow + kt * 32 + g * 8);
        float4 a0 = ap[0], a1 = ap[1];
        float av[8] = {a0.x, a0.y, a0.z, a0.w, a1.x, a1.y, a1.z, a1.w};
        short8v ah, al;
        #pragma unroll
        for (int e = 0; e < 8; ++e) {
            ushort hi = f2bu(av[e]);
            ah[e] = (short)hi;
            al[e] = (short)f2bu(av[e] - bu2f(hi));
        }
        const int kq = kt * 32 + g * 8;
        short8v b0 = *(const short8v*)(vbase + (size_t)(0 * 16 + lm) * 768 + kq);
        short8v b1 = *(const short8v*)(vbase + (size_t)(1 * 16 + lm) * 768 + kq);
        short8v b2 = *(const short8v*)(vbase + (size_t)(2 * 16 + lm) * 768 + kq);
        acc0 = __builtin_amdgcn_mfma_f32_16x16x32_bf16(ah, b0, acc0, 0, 0, 0);
        acc0 = __builtin_amdgcn_mfma_f32_16x16x32_bf16(al, b0, acc0, 0, 0, 0);
        acc1 = __builtin_amdgcn_mfma_f32_16x16x32_bf16(ah, b1, acc1, 0, 0, 0);
        acc1 = __builtin_amdgcn_mfma_f32_16x16x32_bf16(al, b1, acc1, 0, 0, 0);
        acc2 = __builtin_amdgcn_mfma_f32_16x16x32_bf16(ah, b2, acc2, 0, 0, 0);
        acc2 = __builtin_amdgcn_mfma_f32_16x16x32_bf16(al, b2, acc2, 0, 0, 0);
    }
    #pragma unroll
    for (int r = 0; r < 4; ++r) {
        red[wv][0][lane][r] = acc0[r];
        red[wv][1][lane][r] = acc1[r];
        red[wv][2][lane][r] = acc2[r];
    }
    __syncthreads();
    for (int v = tid; v < 768; v += 256) {
        int a = v >> 8, rem = v & 255;
        int l2 = rem >> 2, r = rem & 3;
        float sum = red[0][a][l2][r] + red[1][a][l2][r]
                  + red[2][a][l2][r] + red[3][a][l2][r];
        int lm2 = l2 & 15, g2 = l2 >> 4;
        int row = g2 * 4 + r;
        if (a == 0)      o2[(size_t)(i0 + row) * 192 + h * 16 + lm2] = sum;
        else if (a == 1) o3s[row][lm2] = sum;
        else if (lm2 < 2) o3s[row][16 + lm2] = sum;
    }
    __syncthreads();
    for (int it = tid; it < 96; it += 256) {
        int row = it / 6, pp = it % 6;
        int ii = i0 + row;
        const float* R = &rot[(size_t)ii * 9];
        float x0 = o3s[row][pp * 3 + 0] - trans[ii * 3 + 0];
        float x1 = o3s[row][pp * 3 + 1] - trans[ii * 3 + 1];
        float x2 = o3s[row][pp * 3 + 2] - trans[ii * 3 + 2];
        o3l[(size_t)ii * 216 + h * 18 + pp * 3 + 0] = R[0]*x0 + R[3]*x1 + R[6]*x2;
        o3l[(size_t)ii * 216 + h * 18 + pp * 3 + 1] = R[1]*x0 + R[4]*x1 + R[7]*x2;
        o3l[(size_t)ii * 216 + h * 18 + pp * 3 + 2] = R[2]*x0 + R[5]*x1 + R[8]*x2;
    }
}

// ---------------------------------------------------------------------------
// Kernel 6: partial output projection, grid-parallel (48 it x 6 kt = 288
// blocks). po1 halves summed during staging. part[] -> final_kernel.
// ---------------------------------------------------------------------------
#define KCH 324
__global__ __launch_bounds__(384) void proj_kernel(
    const float* __restrict__ po1, const float* __restrict__ o2,
    const float* __restrict__ o3l,
    const float* __restrict__ W1, const float* __restrict__ W2,
    const float* __restrict__ W3,
    float* __restrict__ part)
{
    const int it = blockIdx.x, kt = blockIdx.y;
    const int tid = threadIdx.x;
    const int kbeg = kt * KCH, kend = kbeg + KCH;
    __shared__ float olds[16][KCH];
    for (int idx = tid; idx < 16 * KCH; idx += 384) {
        int r = idx / KCH, kk = idx % KCH;
        int k = kbeg + kk;
        int i = it * 16 + r;
        float v;
        if (k < 1536)
            v = po1[(size_t)(2 * i) * 1536 + k] + po1[(size_t)(2 * i + 1) * 1536 + k];
        else if (k < 1728)
            v = o2[(size_t)i * 192 + k - 1536];
        else
            v = o3l[(size_t)i * 216 + k - 1728];
        olds[r][kk] = v;
    }
    __syncthreads();
    float acc[16] = {};
    {
        int s0 = kbeg, s1 = (kend < 1536) ? kend : 1536;
        for (int k = s0; k < s1; ++k) {
            float w = W1[(size_t)k * 384 + tid];
            int kk = k - kbeg;
            #pragma unroll
            for (int r = 0; r < 16; ++r) acc[r] += olds[r][kk] * w;
        }
    }
    {
        int s0 = (kbeg > 1536) ? kbeg : 1536, s1 = (kend < 1728) ? kend : 1728;
        for (int k = s0; k < s1; ++k) {
            float w = W2[(size_t)(k - 1536) * 384 + tid];
            int kk = k - kbeg;
            #pragma unroll
            for (int r = 0; r < 16; ++r) acc[r] += olds[r][kk] * w;
        }
    }
    {
        int s0 = (kbeg > 1728) ? kbeg : 1728, s1 = kend;
        for (int k = s0; k < s1; ++k) {
            float w = W3[(size_t)(k - 1728) * 384 + tid];
            int kk = k - kbeg;
            #pragma unroll
            for (int r = 0; r < 16; ++r) acc[r] += olds[r][kk] * w;
        }
    }
    for (int r = 0; r < 16; ++r)
        part[((size_t)kt * LL + it * 16 + r) * 384 + tid] = acc[r];
}

// ---------------------------------------------------------------------------
// Kernel 7: reduce partials + biases
// ---------------------------------------------------------------------------
__global__ __launch_bounds__(256) void final_kernel(
    const float* __restrict__ part,
    const float* __restrict__ b1, const float* __restrict__ b2,
    const float* __restrict__ b3, float* __restrict__ out)
{
    int idx = blockIdx.x * 256 + threadIdx.x;
    if (idx < LL * 384) {
        int n = idx % 384;
        float v = b1[n] + b2[n] + b3[n];
        #pragma unroll
        for (int kt = 0; kt < 6; ++kt) v += part[(size_t)kt * 294912 + idx];
        out[idx] = v;
    }
}

extern "C" void kernel_launch(void* const* d_in, const int* in_sizes, int n_in,
                              void* d_out, int out_size, void* d_ws, size_t ws_size,
                              hipStream_t stream) {
    const float* s     = (const float*)d_in[0];
    const float* z     = (const float*)d_in[1];
    const float* rot   = (const float*)d_in[2];
    const float* trans = (const float*)d_in[3];
    const float* Wq1   = (const float*)d_in[4];
    const float* Wk1   = (const float*)d_in[5];
    const float* Wv1   = (const float*)d_in[6];
    const float* Wq2   = (const float*)d_in[7];
    const float* Wk2   = (const float*)d_in[8];
    const float* Wv3   = (const float*)d_in[9];
    const float* Wz    = (const float*)d_in[10];
    const float* W1    = (const float*)d_in[11];
    const float* b1    = (const float*)d_in[12];
    const float* W2    = (const float*)d_in[13];
    const float* b2    = (const float*)d_in[14];
    const float* W3    = (const float*)d_in[15];
    const float* b3    = (const float*)d_in[16];
    const float* gamma = (const float*)d_in[17];
    float* ws  = (float*)d_ws;
    float* out = (float*)d_out;

    float*  lin  = ws + OFF_LIN;
    ushort* vT   = (ushort*)(ws + OFF_VT);
    ushort* qbh  = (ushort*)(ws + OFF_QBH);
    ushort* qbl  = (ushort*)(ws + OFF_QBL);
    ushort* kbh  = (ushort*)(ws + OFF_KBH);
    ushort* kbl  = (ushort*)(ws + OFF_KBL);
    ushort* wzp  = (ushort*)(ws + OFF_WZ);
    float*  sqwh = ws + OFF_SQWH;
    float*  skwh = ws + OFF_SKWH;
    float*  sx   = ws + OFF_SX;     // scores -> att (in-place) -> dead after ov
    float*  o2   = ws + OFF_O2;
    float*  o3l  = ws + OFF_O3;
    float*  po1  = ws + OFF_PO1;
    float*  part = ws + OFF_SX;     // alias: att dead before proj runs

    dim3 gA(17, 12);
    gemm_lin_kernel<<<gA, 256, 0, stream>>>(s, Wq1, Wk1, Wv1, Wq2, Wk2, Wv3, lin);
    transform_kernel<<<LL, 192, 0, stream>>>(lin, rot, trans, gamma, Wz,
                                             vT, qbh, qbl, kbh, kbl, wzp,
                                             sqwh, skwh);
    dim3 gS(48, 12, 12);
    sextra_kernel<<<gS, 256, 0, stream>>>(qbh, qbl, kbh, kbl, sqwh, skwh, sx);
    attn_kernel<<<LL * 2, 256, 0, stream>>>(z, wzp, sx, po1);
    dim3 gV(48, 12);
    ov_kernel<<<gV, 256, 0, stream>>>(sx, vT, rot, trans, o2, o3l);
    dim3 gC(48, 6);
    proj_kernel<<<gC, 384, 0, stream>>>(po1, o2, o3l, W1, W2, W3, part);
    final_kernel<<<(LL * 384 + 255) / 256, 256, 0, stream>>>(part, b1, b2, b3, out);
}